// Round 9
// baseline (651.724 us; speedup 1.0000x reference)
//
#include <hip/hip_runtime.h>
#include <cstdint>
#include <cstddef>

#define D_MODEL 1024
#define SEQ_LEN 4096
#define NBATCH  4
#define M_ROWS  (NBATCH * SEQ_LEN)   // 16384 rows (b*4096+n)
#define NCHUNK  64
#define CHLEN   64                   // SEQ_LEN / NCHUNK
#define GN_EPS_F 0.00064f

typedef unsigned short u16;
typedef __attribute__((ext_vector_type(4))) float f32x4;
typedef __attribute__((ext_vector_type(8))) __bf16 bf16x8;

__device__ __forceinline__ u16 f2bf(float f) {
  union { float f; uint32_t u; } un; un.f = f;
  uint32_t r = (un.u + 0x7FFFu + ((un.u >> 16) & 1u)) >> 16;  // RNE
  return (u16)r;
}
__device__ __forceinline__ float bf2f(u16 h) {
  union { uint32_t u; float f; } un; un.u = ((uint32_t)h) << 16;
  return un.f;
}
__device__ __forceinline__ float sigm(float y) { return 1.f / (1.f + expf(-y)); }

// async global->LDS, 16B/lane. LDS dst = wave-uniform base (HW adds lane*16).
__device__ __forceinline__ void load_lds16(const u16* g, u16* l) {
  __builtin_amdgcn_global_load_lds(
      (const __attribute__((address_space(1))) void*)g,
      (__attribute__((address_space(3))) void*)l, 16, 0, 0);
}

// ---------------- zero page (8 KB) -------------------------------------------
__global__ __launch_bounds__(1024) void zset(u16* __restrict__ z) {
  ((unsigned long long*)z)[threadIdx.x] = 0ull;  // 1024*8 = 8 KB
}

// ---------------- x f32 -> bf16 ----------------------------------------------
__global__ __launch_bounds__(256) void xgen(
    const float* __restrict__ x, u16* __restrict__ xb) {
  const int gid = blockIdx.x * 256 + threadIdx.x;  // over 4,194,304 float4s... use 2 f4/thread
  const float4 v0 = ((const float4*)x)[gid * 2];
  const float4 v1 = ((const float4*)x)[gid * 2 + 1];
  ushort4 o0, o1;
  o0.x = f2bf(v0.x); o0.y = f2bf(v0.y); o0.z = f2bf(v0.z); o0.w = f2bf(v0.w);
  o1.x = f2bf(v1.x); o1.y = f2bf(v1.y); o1.z = f2bf(v1.z); o1.w = f2bf(v1.w);
  ((ushort4*)xb)[gid * 2] = o0;
  ((ushort4*)xb)[gid * 2 + 1] = o1;
}

// ------- Wall: rows p*1024+j, cols c<1024: W_p[j][c]*(1-m_p[c]);
//                             cols c>=1024: W_p[j][c-1024]*m_p[c-1024]  -------
__global__ __launch_bounds__(256) void wconv2(
    const float* __restrict__ Ww, const float* __restrict__ Wk,
    const float* __restrict__ Wv, const float* __restrict__ Wa,
    const float* __restrict__ Wr, const float* __restrict__ Wg,
    const float* __restrict__ mw, const float* __restrict__ mk,
    const float* __restrict__ mv, const float* __restrict__ ma,
    const float* __restrict__ mr, const float* __restrict__ mg,
    u16* __restrict__ Wall) {
  const int gid = blockIdx.x * 256 + threadIdx.x;  // 6*1024*256 float4-cols
  const int p = gid >> 18;
  const int rem = gid & 262143;
  const int j = rem >> 8;           // row 0..1023
  const int cv = rem & 255;         // float4 col
  const float* W; const float* m;
  switch (p) {
    case 0: W = Ww; m = mw; break; case 1: W = Wk; m = mk; break;
    case 2: W = Wv; m = mv; break; case 3: W = Wa; m = ma; break;
    case 4: W = Wr; m = mr; break; default: W = Wg; m = mg; break;
  }
  const float4 w4 = ((const float4*)W)[j * 256 + cv];
  const float4 m4 = ((const float4*)m)[cv];
  ushort4 lo, hi;
  lo.x = f2bf(w4.x * (1.f - m4.x)); hi.x = f2bf(w4.x * m4.x);
  lo.y = f2bf(w4.y * (1.f - m4.y)); hi.y = f2bf(w4.y * m4.y);
  lo.z = f2bf(w4.z * (1.f - m4.z)); hi.z = f2bf(w4.z * m4.z);
  lo.w = f2bf(w4.w * (1.f - m4.w)); hi.w = f2bf(w4.w * m4.w);
  u16* rowp = Wall + (size_t)(p * 1024 + j) * 2048;
  ((ushort4*)rowp)[cv] = lo;
  ((ushort4*)(rowp + 1024))[cv] = hi;
}

// ---------------- W_out f32 -> bf16 ------------------------------------------
__global__ __launch_bounds__(256) void wconvO(
    const float* __restrict__ W, u16* __restrict__ Wb) {
  const int gid = blockIdx.x * 256 + threadIdx.x;  // 262144 float4s
  const float4 v = ((const float4*)W)[gid];
  ushort4 o;
  o.x = f2bf(v.x); o.y = f2bf(v.y); o.z = f2bf(v.z); o.w = f2bf(v.w);
  ((ushort4*)Wb)[gid] = o;
}

// ---------------- GEMM: out = [x|prev] @ Wall^T  (or h @ Wout^T) -------------
// 128x256 tile, BK=32, 8 waves (2Mx4N), 512 thr, LDS 48KB -> 2 blocks/CU.
// 2 phases/K-tile, counted vmcnt(2), raw s_barrier, setprio, 2-way-free LDS
// swizzle (chunk ^= (row>>1)&3), XCD-chunked n-fastest grid.
// MODE 0: PROJ1 (p: 0=w id, 1=k tanh, 2=v id, 3=alpha sigm)
// MODE 1: PROJ2 (p: 0=r sigm, 1=g sigm)
// MODE 2: OUT   (f32 + bias)
template <int MODE, int KDIM, int NT>
__global__ __launch_bounds__(512, 4) void gemm_bt(
    const u16* __restrict__ A,      // row stride 1024 always
    const u16* __restrict__ Bw,     // [N][KDIM]
    const u16* __restrict__ zpage,
    u16* __restrict__ o0, u16* __restrict__ o1,
    u16* __restrict__ o2, u16* __restrict__ o3,
    float* __restrict__ fout, const float* __restrict__ bias) {
  constexpr int NK = KDIM / 32;
  constexpr int GRID = (M_ROWS / 128) * NT;
  __shared__ __align__(16) u16 AL[2][128 * 32];   // 8 KB each
  __shared__ __align__(16) u16 BL[2][256 * 32];   // 16 KB each
  const int tid = threadIdx.x;
  const int lane = tid & 63;
  const int wid = tid >> 6;
  const int wr = wid >> 2;           // 0..1
  const int wc = wid & 3;            // 0..3
  const int lr = lane & 15;
  const int lk = lane >> 4;

  const int bid = blockIdx.x;
  const int logical = (bid & 7) * (GRID / 8) + (bid >> 3);
  const int m0 = (logical / NT) * 128;
  const int n0 = (logical % NT) * 256;

  // staging: thread t -> row t>>2, 16B-chunk (t&3) ^ ((row>>1)&3)
  const int srow = tid >> 2;
  const int ssw  = ((tid & 3) ^ ((srow >> 1) & 3)) * 8;
  const int arow = m0 + srow;
  const u16* gA_lo = A + (size_t)arow * 1024 + ssw;
  const u16* gA_hi = ((arow & (SEQ_LEN - 1)) == 0)
                         ? (zpage + ssw)
                         : (A + (size_t)(arow - 1) * 1024 + ssw);  // prev row
  const u16* gB0 = Bw + (size_t)(n0 + srow) * KDIM + ssw;
  const u16* gB1 = Bw + (size_t)(n0 + 128 + srow) * KDIM + ssw;

  const int rA = wr * 64;
  const int rB = wc * 64;

  f32x4 acc[4][4];
  const f32x4 z4 = {0.f, 0.f, 0.f, 0.f};
#pragma unroll
  for (int i = 0; i < 4; i++)
#pragma unroll
    for (int j = 0; j < 4; j++) acc[i][j] = z4;

  // prologue: tile 0 into buf 0
  load_lds16(gB0, &BL[0][wid * 512]);
  load_lds16(gB1, &BL[0][4096 + wid * 512]);
  load_lds16(gA_lo, &AL[0][wid * 512]);

  int cur = 0;
  for (int t = 0; t < NK; ++t) {
    const int nxt = cur ^ 1;
    const int ktn = (t + 1) * 32;
    const bool more = (t < NK - 1);
    const u16* uA = AL[cur];
    const u16* uB = BL[cur];
    bf16x8 a[4], b[4];

    // ---- P1: issue next B; counted wait; read frags; MFMA nj 0..1
    if (more) {
      load_lds16(gB0 + ktn, &BL[nxt][wid * 512]);
      load_lds16(gB1 + ktn, &BL[nxt][4096 + wid * 512]);
      asm volatile("s_waitcnt vmcnt(2)" ::: "memory");
    } else {
      asm volatile("s_waitcnt vmcnt(0)" ::: "memory");
    }
    __builtin_amdgcn_s_barrier();
    __builtin_amdgcn_sched_barrier(0);
#pragma unroll
    for (int mi = 0; mi < 4; ++mi) {
      const int R = rA + mi * 16 + lr;
      a[mi] = *(const bf16x8*)&uA[R * 32 + ((lk ^ ((R >> 1) & 3)) << 3)];
    }
#pragma unroll
    for (int nj = 0; nj < 4; ++nj) {
      const int R = rB + nj * 16 + lr;
      b[nj] = *(const bf16x8*)&uB[R * 32 + ((lk ^ ((R >> 1) & 3)) << 3)];
    }
    __builtin_amdgcn_s_setprio(1);
#pragma unroll
    for (int mi = 0; mi < 4; ++mi)
#pragma unroll
      for (int nj = 0; nj < 2; ++nj)
        acc[mi][nj] = __builtin_amdgcn_mfma_f32_16x16x32_bf16(a[mi], b[nj], acc[mi][nj], 0, 0, 0);
    __builtin_amdgcn_s_setprio(0);

    // ---- P2: issue next A; MFMA nj 2..3
    if (more) {
      const u16* sA = (KDIM == 2048 && ktn >= 1024) ? gA_hi + (ktn - 1024)
                                                    : gA_lo + ktn;
      load_lds16(sA, &AL[nxt][wid * 512]);
    }
    __builtin_amdgcn_s_barrier();
    __builtin_amdgcn_s_setprio(1);
#pragma unroll
    for (int mi = 0; mi < 4; ++mi)
#pragma unroll
      for (int nj = 2; nj < 4; ++nj)
        acc[mi][nj] = __builtin_amdgcn_mfma_f32_16x16x32_bf16(a[mi], b[nj], acc[mi][nj], 0, 0, 0);
    __builtin_amdgcn_s_setprio(0);
    cur = nxt;
  }

  // epilogue; C/D layout: col = lane&15, row = (lane>>4)*4 + e  [m89-verified]
  const int p = n0 >> 10;  // projection index (block-uniform)
#pragma unroll
  for (int mi = 0; mi < 4; ++mi) {
#pragma unroll
    for (int nj = 0; nj < 4; ++nj) {
#pragma unroll
      for (int e = 0; e < 4; ++e) {
        const int row = m0 + wr * 64 + mi * 16 + lk * 4 + e;
        const int colg = n0 + wc * 64 + nj * 16 + lr;
        const int col = colg & 1023;
        const size_t idx = (size_t)row * D_MODEL + col;
        const float y = acc[mi][nj][e];
        if constexpr (MODE == 0) {
          switch (p) {
            case 0: o0[idx] = f2bf(y); break;           // w raw
            case 1: o1[idx] = f2bf(tanhf(y)); break;    // k
            case 2: o2[idx] = f2bf(y); break;           // v
            default: o3[idx] = f2bf(sigm(y)); break;    // alpha
          }
        } else if constexpr (MODE == 1) {
          if (p == 0) o0[idx] = f2bf(sigm(y));          // r
          else        o1[idx] = f2bf(sigm(y));          // g
        } else {
          fout[idx] = y + bias[col];
        }
      }
    }
  }
}

// ---------------- u = alpha * k * v (in place over alpha) --------------------
__global__ __launch_bounds__(256) void upass(
    u16* __restrict__ a, const u16* __restrict__ k,
    const u16* __restrict__ v) {
  const int gid = blockIdx.x * 256 + threadIdx.x;  // over 2,097,152 x 8 elems
  uint4 av = ((const uint4*)a)[gid];
  const uint4 kv = ((const uint4*)k)[gid];
  const uint4 vv = ((const uint4*)v)[gid];
  uint4 ov;
  uint32_t* ap = (uint32_t*)&av; const uint32_t* kp = (const uint32_t*)&kv;
  const uint32_t* vp = (const uint32_t*)&vv; uint32_t* op = (uint32_t*)&ov;
#pragma unroll
  for (int i = 0; i < 4; i++) {
    const float a0 = bf2f((u16)(ap[i] & 0xFFFF)), a1 = bf2f((u16)(ap[i] >> 16));
    const float k0 = bf2f((u16)(kp[i] & 0xFFFF)), k1 = bf2f((u16)(kp[i] >> 16));
    const float v0 = bf2f((u16)(vp[i] & 0xFFFF)), v1 = bf2f((u16)(vp[i] >> 16));
    op[i] = (uint32_t)f2bf(a0 * k0 * v0) | ((uint32_t)f2bf(a1 * k1 * v1) << 16);
  }
  ((uint4*)a)[gid] = ov;
}

// ---------------- chunked scan passes ----------------------------------------
__global__ __launch_bounds__(256) void scan1(
    const u16* __restrict__ wraw, const u16* __restrict__ u,
    float* __restrict__ Ac, float* __restrict__ Sc) {
  const int gid = blockIdx.x * 256 + threadIdx.x;  // c*4096 + b*1024 + d
  const int d = gid & 1023;
  const int b = (gid >> 10) & 3;
  const int c = gid >> 12;
  const size_t base = ((size_t)b * SEQ_LEN + (size_t)c * CHLEN) * D_MODEL + d;
  float A = 1.f, S = 0.f;
#pragma unroll 4
  for (int t = 0; t < CHLEN; t++) {
    const size_t off = base + (size_t)t * D_MODEL;
    const float dd = 1.f / (1.f + expf(bf2f(wraw[off])));  // sigmoid(-y)
    S = S * dd + bf2f(u[off]);
    A *= dd;
  }
  Ac[gid] = A;
  Sc[gid] = S;
}

__global__ __launch_bounds__(256) void scan2(
    const float* __restrict__ Ac, const float* __restrict__ Sc,
    float* __restrict__ In) {
  const int gid = blockIdx.x * 256 + threadIdx.x;  // b*1024 + d
  float carry = 0.f;
#pragma unroll 4
  for (int c = 0; c < NCHUNK; c++) {
    const int i = c * 4096 + gid;
    In[i] = carry;
    carry = carry * Ac[i] + Sc[i];
  }
}

__global__ __launch_bounds__(256) void scan3(
    const u16* __restrict__ wraw, const u16* __restrict__ u,
    const u16* __restrict__ r, const float* __restrict__ In,
    u16* __restrict__ mixed) {
  const int gid = blockIdx.x * 256 + threadIdx.x;
  const int d = gid & 1023;
  const int b = (gid >> 10) & 3;
  const int c = gid >> 12;
  const size_t base = ((size_t)b * SEQ_LEN + (size_t)c * CHLEN) * D_MODEL + d;
  float state = In[gid];
#pragma unroll 4
  for (int t = 0; t < CHLEN; t++) {
    const size_t off = base + (size_t)t * D_MODEL;
    const float dd = 1.f / (1.f + expf(bf2f(wraw[off])));  // sigmoid(-y)
    state = state * dd + bf2f(u[off]);
    mixed[off] = f2bf(bf2f(r[off]) * state);
  }
}

// ---------------- GroupNorm(H=16, 64ch) * g -> bf16 ---------------------------
__global__ __launch_bounds__(256) void gnorm(
    const u16* __restrict__ mixed, const u16* __restrict__ g,
    const float* __restrict__ gw, const float* __restrict__ gb,
    u16* __restrict__ h) {
  const int wid = threadIdx.x >> 6;
  const int lane = threadIdx.x & 63;
  const int grp = blockIdx.x * 4 + wid;  // over M_ROWS*16
  const int row = grp >> 4;
  const int hh = grp & 15;
  const int d = hh * 64 + lane;
  const size_t idx = (size_t)row * D_MODEL + d;
  const float v = bf2f(mixed[idx]);
  float s = v, s2 = v * v;
#pragma unroll
  for (int m = 32; m > 0; m >>= 1) {
    s += __shfl_xor(s, m, 64);
    s2 += __shfl_xor(s2, m, 64);
  }
  const float mu = s * (1.f / 64.f);
  const float var = s2 * (1.f / 64.f) - mu * mu;
  const float inv = 1.f / sqrtf(var + GN_EPS_F);
  const float mn = (v - mu) * inv * gw[d] + gb[d];
  h[idx] = f2bf(mn * bf2f(g[idx]));
}

// ---------------- host ---------------------------------------------------------
extern "C" void kernel_launch(void* const* d_in, const int* in_sizes, int n_in,
                              void* d_out, int out_size, void* d_ws, size_t ws_size,
                              hipStream_t stream) {
  (void)in_sizes; (void)n_in; (void)out_size; (void)ws_size;
  const float* x    = (const float*)d_in[0];
  const float* mx_r = (const float*)d_in[1];
  const float* mx_w = (const float*)d_in[2];
  const float* mx_k = (const float*)d_in[3];
  const float* mx_v = (const float*)d_in[4];
  const float* mx_a = (const float*)d_in[5];
  const float* mx_g = (const float*)d_in[6];
  const float* W_r  = (const float*)d_in[7];
  const float* W_w  = (const float*)d_in[8];
  const float* W_k  = (const float*)d_in[9];
  const float* W_v  = (const float*)d_in[10];
  const float* W_a  = (const float*)d_in[11];
  const float* W_g  = (const float*)d_in[12];
  const float* W_o  = (const float*)d_in[13];
  const float* b_out = (const float*)d_in[14];
  const float* gn_w  = (const float*)d_in[15];
  const float* gn_b  = (const float*)d_in[16];

  // Workspace (peak 192 MB):
  //   0: Wall 24 (6144x2048 bf16) | 24: Woutb 2 | 26: Ac 1 | 27: Sc 1
  //   28: Inb 1 | 29: zpage 1 | 32: xbf 32 (later mixed) | 64: wraw 32
  //   96: kbuf 32 (k; then r; then h) | 128: vbuf 32 (v; then g)
  //   160: abuf 32 (alpha; then u in place)
  char* ws = (char*)d_ws;
  const size_t MB = 1024ull * 1024ull;
  u16*   Wall  = (u16*)(ws);
  u16*   Woutb = (u16*)(ws + 24 * MB);
  float* Ac    = (float*)(ws + 26 * MB);
  float* Sc    = (float*)(ws + 27 * MB);
  float* Inb   = (float*)(ws + 28 * MB);
  u16*   zpage = (u16*)(ws + 29 * MB);
  u16*   xbf   = (u16*)(ws + 32 * MB);
  u16*   wraw  = (u16*)(ws + 64 * MB);
  u16*   kbuf  = (u16*)(ws + 96 * MB);
  u16*   vbuf  = (u16*)(ws + 128 * MB);
  u16*   abuf  = (u16*)(ws + 160 * MB);

  zset<<<1, 1024, 0, stream>>>(zpage);
  wconv2<<<6144, 256, 0, stream>>>(W_w, W_k, W_v, W_a, W_r, W_g,
                                   mx_w, mx_k, mx_v, mx_a, mx_r, mx_g, Wall);
  wconvO<<<1024, 256, 0, stream>>>(W_o, Woutb);
  xgen<<<8192, 256, 0, stream>>>(x, xbf);

  // PROJ1: [x|prev] @ Wall[0:4096]^T -> wraw(id), k(tanh), v(id), alpha(sigm)
  gemm_bt<0, 2048, 16><<<2048, 512, 0, stream>>>(
      xbf, Wall, zpage, wraw, kbuf, vbuf, abuf, nullptr, nullptr);
  // u = alpha*k*v in place over abuf
  upass<<<8192, 256, 0, stream>>>(abuf, kbuf, vbuf);
  // PROJ2: [x|prev] @ Wall[4096:6144]^T -> r(sigm)->kbuf, g(sigm)->vbuf
  gemm_bt<1, 2048, 8><<<1024, 512, 0, stream>>>(
      xbf, Wall + (size_t)4096 * 2048, zpage, kbuf, vbuf, nullptr, nullptr,
      nullptr, nullptr);

  // recurrence
  scan1<<<1024, 256, 0, stream>>>(wraw, abuf, Ac, Sc);
  scan2<<<16, 256, 0, stream>>>(Ac, Sc, Inb);
  scan3<<<1024, 256, 0, stream>>>(wraw, abuf, kbuf, Inb, xbf);  // mixed -> xbf

  // groupnorm(mixed)*g -> h -> kbuf (r dead)
  gnorm<<<65536, 256, 0, stream>>>(xbf, vbuf, gn_w, gn_b, kbuf);

  // out = h @ W_out^T + b_out, f32
  gemm_bt<2, 1024, 4><<<512, 512, 0, stream>>>(
      kbuf, Woutb, zpage, nullptr, nullptr, nullptr, nullptr,
      (float*)d_out, b_out);
}

// Round 10
// 606.887 us; speedup vs baseline: 1.0739x; 1.0739x over previous
//
#include <hip/hip_runtime.h>
#include <cstdint>
#include <cstddef>

#define D_MODEL 1024
#define SEQ_LEN 4096
#define NBATCH  4
#define M_ROWS  (NBATCH * SEQ_LEN)   // 16384 rows (b*4096+n)
#define NCHUNK  64
#define CHLEN   64                   // SEQ_LEN / NCHUNK
#define GN_EPS_F 0.00064f

typedef unsigned short u16;
typedef __attribute__((ext_vector_type(4))) float f32x4;
typedef __attribute__((ext_vector_type(8))) __bf16 bf16x8;

enum { ACT_DECAY = 0, ACT_TANH, ACT_VMUL, ACT_U, ACT_SIG, ACT_BIAS, ACT_ID };

__device__ __forceinline__ u16 f2bf(float f) {
  union { float f; uint32_t u; } un; un.f = f;
  uint32_t r = (un.u + 0x7FFFu + ((un.u >> 16) & 1u)) >> 16;  // RNE
  return (u16)r;
}
__device__ __forceinline__ float bf2f(u16 h) {
  union { uint32_t u; float f; } un; un.u = ((uint32_t)h) << 16;
  return un.f;
}
__device__ __forceinline__ float sigm(float y) { return 1.f / (1.f + expf(-y)); }

__device__ __forceinline__ void unp8(const uint4 v, float* f) {
  const uint32_t* p = (const uint32_t*)&v;
#pragma unroll
  for (int i = 0; i < 4; i++) {
    f[2 * i]     = bf2f((u16)(p[i] & 0xFFFF));
    f[2 * i + 1] = bf2f((u16)(p[i] >> 16));
  }
}
__device__ __forceinline__ uint4 pck8(const float* f) {
  uint4 v; uint32_t* p = (uint32_t*)&v;
#pragma unroll
  for (int i = 0; i < 4; i++)
    p[i] = (uint32_t)f2bf(f[2 * i]) | ((uint32_t)f2bf(f[2 * i + 1]) << 16);
  return v;
}

// async global->LDS, 16B/lane. LDS dst = wave-uniform base (HW adds lane*16).
__device__ __forceinline__ void load_lds16(const u16* g, u16* l) {
  __builtin_amdgcn_global_load_lds(
      (const __attribute__((address_space(1))) void*)g,
      (__attribute__((address_space(3))) void*)l, 16, 0, 0);
}

// ---------------- weights f32 -> bf16 (7 matrices, contiguous slots) ----------
__global__ __launch_bounds__(256) void wconv(
    const float* __restrict__ w0, const float* __restrict__ w1,
    const float* __restrict__ w2, const float* __restrict__ w3,
    const float* __restrict__ w4, const float* __restrict__ w5,
    const float* __restrict__ w6, u16* __restrict__ Wb) {
  const int gid = blockIdx.x * 256 + threadIdx.x;  // over 7*262144 float4s
  const int m = gid >> 18;
  const int off = gid & 262143;
  const float* src;
  switch (m) {
    case 0: src = w0; break; case 1: src = w1; break; case 2: src = w2; break;
    case 3: src = w3; break; case 4: src = w4; break; case 5: src = w5; break;
    default: src = w6; break;
  }
  const float4 v = ((const float4*)src)[off];
  ushort4 o;
  o.x = f2bf(v.x); o.y = f2bf(v.y); o.z = f2bf(v.z); o.w = f2bf(v.w);
  ((ushort4*)Wb)[gid] = o;
}

// -------- z = x + (prev - x) * mix for TWO mixes in one x pass -> bf16 -------
__global__ __launch_bounds__(256) void zgen2(
    const float* __restrict__ x, const float* __restrict__ mixA,
    const float* __restrict__ mixB, u16* __restrict__ zA,
    u16* __restrict__ zB) {
  const int gid = blockIdx.x * 256 + threadIdx.x;  // over M_ROWS*D/4 = 4,194,304
  const int dv = gid & 255;                        // float4 index within row
  const int n = (gid >> 8) & (SEQ_LEN - 1);
  const float4 xv = ((const float4*)x)[gid];
  float4 pv = make_float4(0.f, 0.f, 0.f, 0.f);
  if (n > 0) pv = ((const float4*)x)[gid - 256];   // previous token, same batch
  const float4 dxv = make_float4(pv.x - xv.x, pv.y - xv.y, pv.z - xv.z, pv.w - xv.w);
  const float4 ma = ((const float4*)mixA)[dv];
  const float4 mb = ((const float4*)mixB)[dv];
  ushort4 oa, ob;
  oa.x = f2bf(xv.x + dxv.x * ma.x); ob.x = f2bf(xv.x + dxv.x * mb.x);
  oa.y = f2bf(xv.y + dxv.y * ma.y); ob.y = f2bf(xv.y + dxv.y * mb.y);
  oa.z = f2bf(xv.z + dxv.z * ma.z); ob.z = f2bf(xv.z + dxv.z * mb.z);
  oa.w = f2bf(xv.w + dxv.w * ma.w); ob.w = f2bf(xv.w + dxv.w * mb.w);
  ((ushort4*)zA)[gid] = oa;
  ((ushort4*)zB)[gid] = ob;
}

// ---------------- bf16 GEMM: out = A @ W^T  (R8-verified) --------------------
// 128x256 tile, BK=32, 8 waves (2Mx4N), 512 thr, LDS 48KB -> 2 blocks/CU.
// 2 phases/K-tile, counted vmcnt(2), raw s_barrier, setprio, 2-way-free LDS
// swizzle (chunk ^= (row>>1)&3), XCD-chunked n-fastest grid.
template <int ACT>
__global__ __launch_bounds__(512, 4) void gemm_bt(
    const u16* __restrict__ A,   // [M][1024] bf16
    const u16* __restrict__ Bw,  // [1024][1024] bf16 row-major (torch W)
    void* __restrict__ outp,
    const u16* __restrict__ aux,     // kv for ACT_U, k for ACT_VMUL
    const float* __restrict__ bias) {  // for ACT_BIAS
  __shared__ __align__(16) u16 AL[2][128 * 32];   // 8 KB each
  __shared__ __align__(16) u16 BL[2][256 * 32];   // 16 KB each
  const int tid = threadIdx.x;
  const int lane = tid & 63;
  const int wid = tid >> 6;
  const int wr = wid >> 2;           // 0..1  (M half, 64 rows)
  const int wc = wid & 3;            // 0..3  (N quarter, 64 cols)
  const int lr = lane & 15;
  const int lk = lane >> 4;

  // XCD-chunked swizzle: 512 blocks, 8 XCDs, 64 contiguous logical tiles each
  const int bid = blockIdx.x;
  const int wgid = (bid & 7) * 64 + (bid >> 3);
  const int m0 = (wgid >> 2) * 128;
  const int n0 = (wgid & 3) * 256;

  // staging: thread t -> row t>>2 (0..127), 16B-chunk (t&3) ^ ((row>>1)&3)
  const int srow = tid >> 2;
  const int ssw  = ((tid & 3) ^ ((srow >> 1) & 3)) * 8;   // u16 col offset
  const u16* gA  = A  + (size_t)(m0 + srow) * D_MODEL + ssw;
  const u16* gB0 = Bw + (size_t)(n0 + srow) * D_MODEL + ssw;
  const u16* gB1 = Bw + (size_t)(n0 + 128 + srow) * D_MODEL + ssw;
#define SA(bufi, kt) load_lds16(gA  + (kt), &AL[bufi][wid * 512])
#define SB0(bufi, kt) load_lds16(gB0 + (kt), &BL[bufi][wid * 512])
#define SB1(bufi, kt) load_lds16(gB1 + (kt), &BL[bufi][4096 + wid * 512])

  const int rA = wr * 64;
  const int rB = wc * 64;

  f32x4 acc[4][4];
  const f32x4 z4 = {0.f, 0.f, 0.f, 0.f};
#pragma unroll
  for (int i = 0; i < 4; i++)
#pragma unroll
    for (int j = 0; j < 4; j++) acc[i][j] = z4;

  // prologue: tile 0 into buf 0
  SB0(0, 0); SB1(0, 0); SA(0, 0);

  int cur = 0;
  for (int t = 0; t < 32; ++t) {
    const int nxt = cur ^ 1;
    const int ktn = (t + 1) * 32;
    const bool more = (t < 31);
    const u16* uA = AL[cur];
    const u16* uB = BL[cur];
    bf16x8 a[4], b[4];

    // ---- P1: issue next B; counted wait; read all frags; MFMA nj 0..1
    if (more) { SB0(nxt, ktn); SB1(nxt, ktn); }
    if (more) asm volatile("s_waitcnt vmcnt(2)" ::: "memory");
    else      asm volatile("s_waitcnt vmcnt(0)" ::: "memory");
    __builtin_amdgcn_s_barrier();
    __builtin_amdgcn_sched_barrier(0);   // no ds_read hoists above the barrier
#pragma unroll
    for (int mi = 0; mi < 4; ++mi) {
      const int R = rA + mi * 16 + lr;
      a[mi] = *(const bf16x8*)&uA[R * 32 + ((lk ^ ((R >> 1) & 3)) << 3)];
    }
#pragma unroll
    for (int nj = 0; nj < 4; ++nj) {
      const int R = rB + nj * 16 + lr;
      b[nj] = *(const bf16x8*)&uB[R * 32 + ((lk ^ ((R >> 1) & 3)) << 3)];
    }
    __builtin_amdgcn_s_setprio(1);
#pragma unroll
    for (int mi = 0; mi < 4; ++mi)
#pragma unroll
      for (int nj = 0; nj < 2; ++nj)
        acc[mi][nj] = __builtin_amdgcn_mfma_f32_16x16x32_bf16(a[mi], b[nj], acc[mi][nj], 0, 0, 0);
    __builtin_amdgcn_s_setprio(0);

    // ---- P2: issue next A; MFMA nj 2..3
    if (more) SA(nxt, ktn);
    __builtin_amdgcn_s_barrier();
    __builtin_amdgcn_s_setprio(1);
#pragma unroll
    for (int mi = 0; mi < 4; ++mi)
#pragma unroll
      for (int nj = 2; nj < 4; ++nj)
        acc[mi][nj] = __builtin_amdgcn_mfma_f32_16x16x32_bf16(a[mi], b[nj], acc[mi][nj], 0, 0, 0);
    __builtin_amdgcn_s_setprio(0);
    cur = nxt;
  }
#undef SA
#undef SB0
#undef SB1

  // epilogue; C/D layout: col = lane&15, row = (lane>>4)*4 + e  [m89-verified]
#pragma unroll
  for (int mi = 0; mi < 4; ++mi) {
#pragma unroll
    for (int nj = 0; nj < 4; ++nj) {
#pragma unroll
      for (int e = 0; e < 4; ++e) {
        const int row = m0 + wr * 64 + mi * 16 + lk * 4 + e;
        const int col = n0 + wc * 64 + nj * 16 + lr;
        const size_t idx = (size_t)row * D_MODEL + col;
        const float y = acc[mi][nj][e];
        if constexpr (ACT == ACT_ID) {
          ((u16*)outp)[idx] = f2bf(y);                           // raw lin (w)
        } else if constexpr (ACT == ACT_TANH) {
          ((u16*)outp)[idx] = f2bf(tanhf(y));
        } else if constexpr (ACT == ACT_VMUL) {
          ((u16*)outp)[idx] = f2bf(y * bf2f(aux[idx]));          // kv = v * k
        } else if constexpr (ACT == ACT_U) {
          ((u16*)outp)[idx] = f2bf(sigm(y) * bf2f(aux[idx]));    // u = alpha * kv
        } else if constexpr (ACT == ACT_SIG) {
          ((u16*)outp)[idx] = f2bf(sigm(y));
        } else {  // ACT_BIAS
          ((float*)outp)[idx] = y + bias[col];
        }
      }
    }
  }
}

// ---------------- chunked scan, 8 channels/thread ----------------------------
// thread -> (c, b, dv): 8 consecutive d channels, uint4 (bf16x8) loads.
__global__ __launch_bounds__(256) void scan1(
    const u16* __restrict__ wraw, const u16* __restrict__ u,
    float* __restrict__ Ac, float* __restrict__ Sc) {
  const int gid = blockIdx.x * 256 + threadIdx.x;  // 32768: c(64) b(4) dv(128)
  const int dv = gid & 127;
  const int b = (gid >> 7) & 3;
  const int c = gid >> 9;
  const uint4* w4 = (const uint4*)wraw;
  const uint4* u4 = (const uint4*)u;
  size_t off = ((size_t)b * SEQ_LEN + (size_t)c * CHLEN) * 128 + dv;  // uint4 units
  float A[8], S[8];
#pragma unroll
  for (int i = 0; i < 8; i++) { A[i] = 1.f; S[i] = 0.f; }
#pragma unroll 2
  for (int t = 0; t < CHLEN; t++, off += 128) {
    float wv[8], uv[8];
    unp8(w4[off], wv);
    unp8(u4[off], uv);
#pragma unroll
    for (int i = 0; i < 8; i++) {
      const float dd = 1.f / (1.f + expf(wv[i]));  // sigmoid(-y)
      S[i] = S[i] * dd + uv[i];
      A[i] *= dd;
    }
  }
  const int o4 = c * 1024 + b * 256 + dv * 2;  // float4 units, matches scan2 layout
  ((float4*)Ac)[o4]     = make_float4(A[0], A[1], A[2], A[3]);
  ((float4*)Ac)[o4 + 1] = make_float4(A[4], A[5], A[6], A[7]);
  ((float4*)Sc)[o4]     = make_float4(S[0], S[1], S[2], S[3]);
  ((float4*)Sc)[o4 + 1] = make_float4(S[4], S[5], S[6], S[7]);
}

__global__ __launch_bounds__(256) void scan2(
    const float* __restrict__ Ac, const float* __restrict__ Sc,
    float* __restrict__ In) {
  const int gid = blockIdx.x * 256 + threadIdx.x;  // b*1024 + d, 4096 total
  float carry = 0.f;
#pragma unroll 4
  for (int c = 0; c < NCHUNK; c++) {
    const int i = c * 4096 + gid;
    In[i] = carry;
    carry = carry * Ac[i] + Sc[i];
  }
}

__global__ __launch_bounds__(256) void scan3(
    const u16* __restrict__ wraw, const u16* __restrict__ u,
    const u16* __restrict__ r, const float* __restrict__ In,
    u16* __restrict__ mixed) {
  const int gid = blockIdx.x * 256 + threadIdx.x;  // 32768: c(64) b(4) dv(128)
  const int dv = gid & 127;
  const int b = (gid >> 7) & 3;
  const int c = gid >> 9;
  const uint4* w4 = (const uint4*)wraw;
  const uint4* u4 = (const uint4*)u;
  const uint4* r4 = (const uint4*)r;
  uint4* m4 = (uint4*)mixed;
  size_t off = ((size_t)b * SEQ_LEN + (size_t)c * CHLEN) * 128 + dv;
  const int o4 = c * 1024 + b * 256 + dv * 2;
  const float4 s0 = ((const float4*)In)[o4];
  const float4 s1 = ((const float4*)In)[o4 + 1];
  float S[8] = {s0.x, s0.y, s0.z, s0.w, s1.x, s1.y, s1.z, s1.w};
#pragma unroll 2
  for (int t = 0; t < CHLEN; t++, off += 128) {
    float wv[8], uv[8], rv[8], mv[8];
    unp8(w4[off], wv);
    unp8(u4[off], uv);
    unp8(r4[off], rv);
#pragma unroll
    for (int i = 0; i < 8; i++) {
      const float dd = 1.f / (1.f + expf(wv[i]));  // sigmoid(-y)
      S[i] = S[i] * dd + uv[i];
      mv[i] = rv[i] * S[i];
    }
    m4[off] = pck8(mv);
  }
}

// ------- GroupNorm(H=16, 64ch) * g -> bf16; 8 ch/thread, 8-lane subgroup ----
__global__ __launch_bounds__(256) void gnorm(
    const u16* __restrict__ mixed, const u16* __restrict__ g,
    const float* __restrict__ gw, const float* __restrict__ gb,
    u16* __restrict__ h) {
  const int G = blockIdx.x * 32 + (threadIdx.x >> 3);  // group id, 262144 total
  const int sub = threadIdx.x & 7;
  const int row = G >> 4;
  const int hh = G & 15;
  const int d0 = hh * 64 + sub * 8;
  const size_t i4 = ((size_t)row * D_MODEL + d0) >> 3;  // uint4 units
  float mv[8], gv[8];
  unp8(((const uint4*)mixed)[i4], mv);
  unp8(((const uint4*)g)[i4], gv);
  float s = 0.f, s2 = 0.f;
#pragma unroll
  for (int i = 0; i < 8; i++) { s += mv[i]; s2 += mv[i] * mv[i]; }
#pragma unroll
  for (int m = 1; m < 8; m <<= 1) {   // within 8-lane subgroup
    s += __shfl_xor(s, m, 64);
    s2 += __shfl_xor(s2, m, 64);
  }
  const float mu = s * (1.f / 64.f);
  const float var = s2 * (1.f / 64.f) - mu * mu;
  const float inv = 1.f / sqrtf(var + GN_EPS_F);
  const float4 gw0 = ((const float4*)gw)[d0 >> 2], gw1 = ((const float4*)gw)[(d0 >> 2) + 1];
  const float4 gb0 = ((const float4*)gb)[d0 >> 2], gb1 = ((const float4*)gb)[(d0 >> 2) + 1];
  const float W[8] = {gw0.x, gw0.y, gw0.z, gw0.w, gw1.x, gw1.y, gw1.z, gw1.w};
  const float Bb[8] = {gb0.x, gb0.y, gb0.z, gb0.w, gb1.x, gb1.y, gb1.z, gb1.w};
  float ov[8];
#pragma unroll
  for (int i = 0; i < 8; i++)
    ov[i] = ((mv[i] - mu) * inv * W[i] + Bb[i]) * gv[i];
  ((uint4*)h)[i4] = pck8(ov);
}

// ---------------- host ---------------------------------------------------------
extern "C" void kernel_launch(void* const* d_in, const int* in_sizes, int n_in,
                              void* d_out, int out_size, void* d_ws, size_t ws_size,
                              hipStream_t stream) {
  (void)in_sizes; (void)n_in; (void)out_size; (void)ws_size;
  const float* x    = (const float*)d_in[0];
  const float* mx_r = (const float*)d_in[1];
  const float* mx_w = (const float*)d_in[2];
  const float* mx_k = (const float*)d_in[3];
  const float* mx_v = (const float*)d_in[4];
  const float* mx_a = (const float*)d_in[5];
  const float* mx_g = (const float*)d_in[6];
  const float* W_r  = (const float*)d_in[7];
  const float* W_w  = (const float*)d_in[8];
  const float* W_k  = (const float*)d_in[9];
  const float* W_v  = (const float*)d_in[10];
  const float* W_a  = (const float*)d_in[11];
  const float* W_g  = (const float*)d_in[12];
  const float* W_o  = (const float*)d_in[13];
  const float* b_out = (const float*)d_in[14];
  const float* gn_w  = (const float*)d_in[15];
  const float* gn_b  = (const float*)d_in[16];

  // Workspace plan (209 MB; all bf16 intermediates):
  //   0: Wb 14 | 14: Ac 1 | 15: Sc 1 | 16: z1 32 (z_w/z_v/z_r; later mixed)
  //   48: z2 32 (z_k/z_a/z_g; later h) | 80: wraw 32 | 112: ubuf 32
  //   144: kbuf 32 (k; later r) | 176: vbuf 32 (kv; later g) | 208: In 1
  char* ws = (char*)d_ws;
  const size_t MB = 1024ull * 1024ull;
  u16*   Wb   = (u16*)(ws);
  float* Ac   = (float*)(ws + 14 * MB);
  float* Sc   = (float*)(ws + 15 * MB);
  u16*   z1   = (u16*)(ws + 16 * MB);
  u16*   z2   = (u16*)(ws + 48 * MB);
  u16*   wraw = (u16*)(ws + 80 * MB);
  u16*   ubuf = (u16*)(ws + 112 * MB);
  u16*   kbuf = (u16*)(ws + 144 * MB);
  u16*   vbuf = (u16*)(ws + 176 * MB);
  float* Inb  = (float*)(ws + 208 * MB);

  wconv<<<7168, 256, 0, stream>>>(W_r, W_w, W_k, W_v, W_a, W_g, W_o, Wb);

  // pair 1: z_w, z_k
  zgen2<<<16384, 256, 0, stream>>>(x, mx_w, mx_k, z1, z2);
  gemm_bt<ACT_ID><<<512, 512, 0, stream>>>(z1, Wb + 1 * 1048576, wraw, nullptr, nullptr);
  gemm_bt<ACT_TANH><<<512, 512, 0, stream>>>(z2, Wb + 2 * 1048576, kbuf, nullptr, nullptr);
  // pair 2: z_v, z_a
  zgen2<<<16384, 256, 0, stream>>>(x, mx_v, mx_a, z1, z2);
  gemm_bt<ACT_VMUL><<<512, 512, 0, stream>>>(z1, Wb + 3 * 1048576, vbuf, kbuf, nullptr);
  gemm_bt<ACT_U><<<512, 512, 0, stream>>>(z2, Wb + 4 * 1048576, ubuf, vbuf, nullptr);
  // pair 3: z_r, z_g
  zgen2<<<16384, 256, 0, stream>>>(x, mx_r, mx_g, z1, z2);
  gemm_bt<ACT_SIG><<<512, 512, 0, stream>>>(z1, Wb + 0, kbuf, nullptr, nullptr);
  gemm_bt<ACT_SIG><<<512, 512, 0, stream>>>(z2, Wb + 5 * 1048576, vbuf, nullptr, nullptr);

  // recurrence (chunked parallel scan); mixed (bf16) -> z1
  scan1<<<128, 256, 0, stream>>>(wraw, ubuf, Ac, Sc);
  scan2<<<16, 256, 0, stream>>>(Ac, Sc, Inb);
  scan3<<<128, 256, 0, stream>>>(wraw, ubuf, kbuf, Inb, z1);

  // groupnorm(mixed) * g -> h (bf16, into z2)
  gnorm<<<8192, 256, 0, stream>>>(z1, vbuf, gn_w, gn_b, z2);

  // out = h @ W_out^T + b_out, f32
  gemm_bt<ACT_BIAS><<<512, 512, 0, stream>>>(z2, Wb + 6 * 1048576, (float*)d_out, nullptr, b_out);
}

// Round 11
// 478.595 us; speedup vs baseline: 1.3617x; 1.2681x over previous
//
#include <hip/hip_runtime.h>
#include <cstdint>
#include <cstddef>

#define D_MODEL 1024
#define SEQ_LEN 4096
#define NBATCH  4
#define M_ROWS  (NBATCH * SEQ_LEN)   // 16384 rows (b*4096+n)
#define NCHUNK  64
#define CHLEN   64                   // SEQ_LEN / NCHUNK
#define GN_EPS_F 0.00064f

typedef unsigned short u16;
typedef __attribute__((ext_vector_type(4))) float f32x4;
typedef __attribute__((ext_vector_type(8))) __bf16 bf16x8;

enum { ACT_DECAY = 0, ACT_TANH, ACT_VMUL, ACT_U, ACT_SIG, ACT_BIAS, ACT_ID };

__device__ __forceinline__ u16 f2bf(float f) {
  union { float f; uint32_t u; } un; un.f = f;
  uint32_t r = (un.u + 0x7FFFu + ((un.u >> 16) & 1u)) >> 16;  // RNE
  return (u16)r;
}
__device__ __forceinline__ float bf2f(u16 h) {
  union { uint32_t u; float f; } un; un.u = ((uint32_t)h) << 16;
  return un.f;
}
__device__ __forceinline__ float sigm(float y) { return 1.f / (1.f + expf(-y)); }

__device__ __forceinline__ void unp8(const uint4 v, float* f) {
  const uint32_t* p = (const uint32_t*)&v;
#pragma unroll
  for (int i = 0; i < 4; i++) {
    f[2 * i]     = bf2f((u16)(p[i] & 0xFFFF));
    f[2 * i + 1] = bf2f((u16)(p[i] >> 16));
  }
}
__device__ __forceinline__ uint4 pck8(const float* f) {
  uint4 v; uint32_t* p = (uint32_t*)&v;
#pragma unroll
  for (int i = 0; i < 4; i++)
    p[i] = (uint32_t)f2bf(f[2 * i]) | ((uint32_t)f2bf(f[2 * i + 1]) << 16);
  return v;
}

// async global->LDS, 16B/lane. LDS dst = wave-uniform base (HW adds lane*16).
__device__ __forceinline__ void load_lds16(const u16* g, u16* l) {
  __builtin_amdgcn_global_load_lds(
      (const __attribute__((address_space(1))) void*)g,
      (__attribute__((address_space(3))) void*)l, 16, 0, 0);
}

// ---------------- weights f32 -> bf16 (7 matrices, contiguous slots) ----------
__global__ __launch_bounds__(256) void wconv(
    const float* __restrict__ w0, const float* __restrict__ w1,
    const float* __restrict__ w2, const float* __restrict__ w3,
    const float* __restrict__ w4, const float* __restrict__ w5,
    const float* __restrict__ w6, u16* __restrict__ Wb) {
  const int gid = blockIdx.x * 256 + threadIdx.x;  // over 7*262144 float4s
  const int m = gid >> 18;
  const int off = gid & 262143;
  const float* src;
  switch (m) {
    case 0: src = w0; break; case 1: src = w1; break; case 2: src = w2; break;
    case 3: src = w3; break; case 4: src = w4; break; case 5: src = w5; break;
    default: src = w6; break;
  }
  const float4 v = ((const float4*)src)[off];
  ushort4 o;
  o.x = f2bf(v.x); o.y = f2bf(v.y); o.z = f2bf(v.z); o.w = f2bf(v.w);
  ((ushort4*)Wb)[gid] = o;
}

// -------- z = x + (prev - x) * mix for TWO mixes in one x pass -> bf16 -------
__global__ __launch_bounds__(256) void zgen2(
    const float* __restrict__ x, const float* __restrict__ mixA,
    const float* __restrict__ mixB, u16* __restrict__ zA,
    u16* __restrict__ zB) {
  const int gid = blockIdx.x * 256 + threadIdx.x;  // over M_ROWS*D/4 = 4,194,304
  const int dv = gid & 255;                        // float4 index within row
  const int n = (gid >> 8) & (SEQ_LEN - 1);
  const float4 xv = ((const float4*)x)[gid];
  float4 pv = make_float4(0.f, 0.f, 0.f, 0.f);
  if (n > 0) pv = ((const float4*)x)[gid - 256];   // previous token, same batch
  const float4 dxv = make_float4(pv.x - xv.x, pv.y - xv.y, pv.z - xv.z, pv.w - xv.w);
  const float4 ma = ((const float4*)mixA)[dv];
  const float4 mb = ((const float4*)mixB)[dv];
  ushort4 oa, ob;
  oa.x = f2bf(xv.x + dxv.x * ma.x); ob.x = f2bf(xv.x + dxv.x * mb.x);
  oa.y = f2bf(xv.y + dxv.y * ma.y); ob.y = f2bf(xv.y + dxv.y * mb.y);
  oa.z = f2bf(xv.z + dxv.z * ma.z); ob.z = f2bf(xv.z + dxv.z * mb.z);
  oa.w = f2bf(xv.w + dxv.w * ma.w); ob.w = f2bf(xv.w + dxv.w * mb.w);
  ((ushort4*)zA)[gid] = oa;
  ((ushort4*)zB)[gid] = ob;
}

// ---------------- bf16 GEMM: out = A @ W^T  (R8-verified) --------------------
// 128x256 tile, BK=32, 8 waves (2Mx4N), 512 thr, LDS 48KB -> 2 blocks/CU.
// 2 phases/K-tile, counted vmcnt(2), raw s_barrier, setprio, 2-way-free LDS
// swizzle (chunk ^= (row>>1)&3), XCD-chunked n-fastest grid.
template <int ACT>
__global__ __launch_bounds__(512, 4) void gemm_bt(
    const u16* __restrict__ A,   // [M][1024] bf16
    const u16* __restrict__ Bw,  // [1024][1024] bf16 row-major (torch W)
    void* __restrict__ outp,
    const u16* __restrict__ aux,     // kv for ACT_U, k for ACT_VMUL
    const float* __restrict__ bias) {  // for ACT_BIAS
  __shared__ __align__(16) u16 AL[2][128 * 32];   // 8 KB each
  __shared__ __align__(16) u16 BL[2][256 * 32];   // 16 KB each
  const int tid = threadIdx.x;
  const int lane = tid & 63;
  const int wid = tid >> 6;
  const int wr = wid >> 2;           // 0..1  (M half, 64 rows)
  const int wc = wid & 3;            // 0..3  (N quarter, 64 cols)
  const int lr = lane & 15;
  const int lk = lane >> 4;

  // XCD-chunked swizzle: 512 blocks, 8 XCDs, 64 contiguous logical tiles each
  const int bid = blockIdx.x;
  const int wgid = (bid & 7) * 64 + (bid >> 3);
  const int m0 = (wgid >> 2) * 128;
  const int n0 = (wgid & 3) * 256;

  // staging: thread t -> row t>>2 (0..127), 16B-chunk (t&3) ^ ((row>>1)&3)
  const int srow = tid >> 2;
  const int ssw  = ((tid & 3) ^ ((srow >> 1) & 3)) * 8;   // u16 col offset
  const u16* gA  = A  + (size_t)(m0 + srow) * D_MODEL + ssw;
  const u16* gB0 = Bw + (size_t)(n0 + srow) * D_MODEL + ssw;
  const u16* gB1 = Bw + (size_t)(n0 + 128 + srow) * D_MODEL + ssw;
#define SA(bufi, kt) load_lds16(gA  + (kt), &AL[bufi][wid * 512])
#define SB0(bufi, kt) load_lds16(gB0 + (kt), &BL[bufi][wid * 512])
#define SB1(bufi, kt) load_lds16(gB1 + (kt), &BL[bufi][4096 + wid * 512])

  const int rA = wr * 64;
  const int rB = wc * 64;

  f32x4 acc[4][4];
  const f32x4 z4 = {0.f, 0.f, 0.f, 0.f};
#pragma unroll
  for (int i = 0; i < 4; i++)
#pragma unroll
    for (int j = 0; j < 4; j++) acc[i][j] = z4;

  // prologue: tile 0 into buf 0
  SB0(0, 0); SB1(0, 0); SA(0, 0);

  int cur = 0;
  for (int t = 0; t < 32; ++t) {
    const int nxt = cur ^ 1;
    const int ktn = (t + 1) * 32;
    const bool more = (t < 31);
    const u16* uA = AL[cur];
    const u16* uB = BL[cur];
    bf16x8 a[4], b[4];

    // ---- P1: issue next B; counted wait; read all frags; MFMA nj 0..1
    if (more) { SB0(nxt, ktn); SB1(nxt, ktn); }
    if (more) asm volatile("s_waitcnt vmcnt(2)" ::: "memory");
    else      asm volatile("s_waitcnt vmcnt(0)" ::: "memory");
    __builtin_amdgcn_s_barrier();
    __builtin_amdgcn_sched_barrier(0);   // no ds_read hoists above the barrier
#pragma unroll
    for (int mi = 0; mi < 4; ++mi) {
      const int R = rA + mi * 16 + lr;
      a[mi] = *(const bf16x8*)&uA[R * 32 + ((lk ^ ((R >> 1) & 3)) << 3)];
    }
#pragma unroll
    for (int nj = 0; nj < 4; ++nj) {
      const int R = rB + nj * 16 + lr;
      b[nj] = *(const bf16x8*)&uB[R * 32 + ((lk ^ ((R >> 1) & 3)) << 3)];
    }
    __builtin_amdgcn_s_setprio(1);
#pragma unroll
    for (int mi = 0; mi < 4; ++mi)
#pragma unroll
      for (int nj = 0; nj < 2; ++nj)
        acc[mi][nj] = __builtin_amdgcn_mfma_f32_16x16x32_bf16(a[mi], b[nj], acc[mi][nj], 0, 0, 0);
    __builtin_amdgcn_s_setprio(0);

    // ---- P2: issue next A; MFMA nj 2..3
    if (more) SA(nxt, ktn);
    __builtin_amdgcn_s_barrier();
    __builtin_amdgcn_s_setprio(1);
#pragma unroll
    for (int mi = 0; mi < 4; ++mi)
#pragma unroll
      for (int nj = 2; nj < 4; ++nj)
        acc[mi][nj] = __builtin_amdgcn_mfma_f32_16x16x32_bf16(a[mi], b[nj], acc[mi][nj], 0, 0, 0);
    __builtin_amdgcn_s_setprio(0);
    cur = nxt;
  }
#undef SA
#undef SB0
#undef SB1

  // epilogue; C/D layout: col = lane&15, row = (lane>>4)*4 + e  [m89-verified]
#pragma unroll
  for (int mi = 0; mi < 4; ++mi) {
#pragma unroll
    for (int nj = 0; nj < 4; ++nj) {
#pragma unroll
      for (int e = 0; e < 4; ++e) {
        const int row = m0 + wr * 64 + mi * 16 + lk * 4 + e;
        const int col = n0 + wc * 64 + nj * 16 + lr;
        const size_t idx = (size_t)row * D_MODEL + col;
        const float y = acc[mi][nj][e];
        if constexpr (ACT == ACT_ID) {
          ((u16*)outp)[idx] = f2bf(y);                           // raw lin (w)
        } else if constexpr (ACT == ACT_TANH) {
          ((u16*)outp)[idx] = f2bf(tanhf(y));
        } else if constexpr (ACT == ACT_VMUL) {
          ((u16*)outp)[idx] = f2bf(y * bf2f(aux[idx]));          // kv = v * k
        } else if constexpr (ACT == ACT_U) {
          ((u16*)outp)[idx] = f2bf(sigm(y) * bf2f(aux[idx]));    // u = alpha * kv
        } else if constexpr (ACT == ACT_SIG) {
          ((u16*)outp)[idx] = f2bf(sigm(y));
        } else {  // ACT_BIAS
          ((float*)outp)[idx] = y + bias[col];
        }
      }
    }
  }
}

// ------- chunked scan, scalar 1 ch/thread (R7-verified: TLP-bound regime) ----
__global__ __launch_bounds__(256) void scan1(
    const u16* __restrict__ wraw, const u16* __restrict__ u,
    float* __restrict__ Ac, float* __restrict__ Sc) {
  const int gid = blockIdx.x * 256 + threadIdx.x;  // c*4096 + b*1024 + d
  const int d = gid & 1023;
  const int b = (gid >> 10) & 3;
  const int c = gid >> 12;
  const size_t base = ((size_t)b * SEQ_LEN + (size_t)c * CHLEN) * D_MODEL + d;
  float A = 1.f, S = 0.f;
#pragma unroll 4
  for (int t = 0; t < CHLEN; t++) {
    const size_t off = base + (size_t)t * D_MODEL;
    const float dd = 1.f / (1.f + expf(bf2f(wraw[off])));  // sigmoid(-y)
    S = S * dd + bf2f(u[off]);
    A *= dd;
  }
  Ac[gid] = A;
  Sc[gid] = S;
}

__global__ __launch_bounds__(256) void scan2(
    const float* __restrict__ Ac, const float* __restrict__ Sc,
    float* __restrict__ In) {
  const int gid = blockIdx.x * 256 + threadIdx.x;  // b*1024 + d, 4096 total
  float carry = 0.f;
#pragma unroll 4
  for (int c = 0; c < NCHUNK; c++) {
    const int i = c * 4096 + gid;
    In[i] = carry;
    carry = carry * Ac[i] + Sc[i];
  }
}

__global__ __launch_bounds__(256) void scan3(
    const u16* __restrict__ wraw, const u16* __restrict__ u,
    const u16* __restrict__ r, const float* __restrict__ In,
    u16* __restrict__ mixed) {
  const int gid = blockIdx.x * 256 + threadIdx.x;
  const int d = gid & 1023;
  const int b = (gid >> 10) & 3;
  const int c = gid >> 12;
  const size_t base = ((size_t)b * SEQ_LEN + (size_t)c * CHLEN) * D_MODEL + d;
  float state = In[gid];
#pragma unroll 4
  for (int t = 0; t < CHLEN; t++) {
    const size_t off = base + (size_t)t * D_MODEL;
    const float dd = 1.f / (1.f + expf(bf2f(wraw[off])));  // sigmoid(-y)
    state = state * dd + bf2f(u[off]);
    mixed[off] = f2bf(bf2f(r[off]) * state);
  }
}

// ------- GroupNorm(H=16, 64ch) * g -> bf16; 8 ch/thread, 8-lane subgroup ----
__global__ __launch_bounds__(256) void gnorm(
    const u16* __restrict__ mixed, const u16* __restrict__ g,
    const float* __restrict__ gw, const float* __restrict__ gb,
    u16* __restrict__ h) {
  const int G = blockIdx.x * 32 + (threadIdx.x >> 3);  // group id, 262144 total
  const int sub = threadIdx.x & 7;
  const int row = G >> 4;
  const int hh = G & 15;
  const int d0 = hh * 64 + sub * 8;
  const size_t i4 = ((size_t)row * D_MODEL + d0) >> 3;  // uint4 units
  float mv[8], gv[8];
  unp8(((const uint4*)mixed)[i4], mv);
  unp8(((const uint4*)g)[i4], gv);
  float s = 0.f, s2 = 0.f;
#pragma unroll
  for (int i = 0; i < 8; i++) { s += mv[i]; s2 += mv[i] * mv[i]; }
#pragma unroll
  for (int m = 1; m < 8; m <<= 1) {   // within 8-lane subgroup
    s += __shfl_xor(s, m, 64);
    s2 += __shfl_xor(s2, m, 64);
  }
  const float mu = s * (1.f / 64.f);
  const float var = s2 * (1.f / 64.f) - mu * mu;
  const float inv = 1.f / sqrtf(var + GN_EPS_F);
  const float4 gw0 = ((const float4*)gw)[d0 >> 2], gw1 = ((const float4*)gw)[(d0 >> 2) + 1];
  const float4 gb0 = ((const float4*)gb)[d0 >> 2], gb1 = ((const float4*)gb)[(d0 >> 2) + 1];
  const float W[8] = {gw0.x, gw0.y, gw0.z, gw0.w, gw1.x, gw1.y, gw1.z, gw1.w};
  const float Bb[8] = {gb0.x, gb0.y, gb0.z, gb0.w, gb1.x, gb1.y, gb1.z, gb1.w};
  float ov[8];
#pragma unroll
  for (int i = 0; i < 8; i++)
    ov[i] = ((mv[i] - mu) * inv * W[i] + Bb[i]) * gv[i];
  ((uint4*)h)[i4] = pck8(ov);
}

// ---------------- host ---------------------------------------------------------
extern "C" void kernel_launch(void* const* d_in, const int* in_sizes, int n_in,
                              void* d_out, int out_size, void* d_ws, size_t ws_size,
                              hipStream_t stream) {
  (void)in_sizes; (void)n_in; (void)out_size; (void)ws_size;
  const float* x    = (const float*)d_in[0];
  const float* mx_r = (const float*)d_in[1];
  const float* mx_w = (const float*)d_in[2];
  const float* mx_k = (const float*)d_in[3];
  const float* mx_v = (const float*)d_in[4];
  const float* mx_a = (const float*)d_in[5];
  const float* mx_g = (const float*)d_in[6];
  const float* W_r  = (const float*)d_in[7];
  const float* W_w  = (const float*)d_in[8];
  const float* W_k  = (const float*)d_in[9];
  const float* W_v  = (const float*)d_in[10];
  const float* W_a  = (const float*)d_in[11];
  const float* W_g  = (const float*)d_in[12];
  const float* W_o  = (const float*)d_in[13];
  const float* b_out = (const float*)d_in[14];
  const float* gn_w  = (const float*)d_in[15];
  const float* gn_b  = (const float*)d_in[16];

  // Workspace plan (209 MB; all bf16 intermediates):
  //   0: Wb 14 | 14: Ac 1 | 15: Sc 1 | 16: z1 32 (z_w/z_v/z_r; later mixed)
  //   48: z2 32 (z_k/z_a/z_g; later h) | 80: wraw 32 | 112: ubuf 32
  //   144: kbuf 32 (k; later r) | 176: vbuf 32 (kv; later g) | 208: In 1
  char* ws = (char*)d_ws;
  const size_t MB = 1024ull * 1024ull;
  u16*   Wb   = (u16*)(ws);
  float* Ac   = (float*)(ws + 14 * MB);
  float* Sc   = (float*)(ws + 15 * MB);
  u16*   z1   = (u16*)(ws + 16 * MB);
  u16*   z2   = (u16*)(ws + 48 * MB);
  u16*   wraw = (u16*)(ws + 80 * MB);
  u16*   ubuf = (u16*)(ws + 112 * MB);
  u16*   kbuf = (u16*)(ws + 144 * MB);
  u16*   vbuf = (u16*)(ws + 176 * MB);
  float* Inb  = (float*)(ws + 208 * MB);

  wconv<<<7168, 256, 0, stream>>>(W_r, W_w, W_k, W_v, W_a, W_g, W_o, Wb);

  // pair 1: z_w, z_k
  zgen2<<<16384, 256, 0, stream>>>(x, mx_w, mx_k, z1, z2);
  gemm_bt<ACT_ID><<<512, 512, 0, stream>>>(z1, Wb + 1 * 1048576, wraw, nullptr, nullptr);
  gemm_bt<ACT_TANH><<<512, 512, 0, stream>>>(z2, Wb + 2 * 1048576, kbuf, nullptr, nullptr);
  // pair 2: z_v, z_a
  zgen2<<<16384, 256, 0, stream>>>(x, mx_v, mx_a, z1, z2);
  gemm_bt<ACT_VMUL><<<512, 512, 0, stream>>>(z1, Wb + 3 * 1048576, vbuf, kbuf, nullptr);
  gemm_bt<ACT_U><<<512, 512, 0, stream>>>(z2, Wb + 4 * 1048576, ubuf, vbuf, nullptr);
  // pair 3: z_r, z_g
  zgen2<<<16384, 256, 0, stream>>>(x, mx_r, mx_g, z1, z2);
  gemm_bt<ACT_SIG><<<512, 512, 0, stream>>>(z1, Wb + 0, kbuf, nullptr, nullptr);
  gemm_bt<ACT_SIG><<<512, 512, 0, stream>>>(z2, Wb + 5 * 1048576, vbuf, nullptr, nullptr);

  // recurrence (chunked parallel scan); mixed (bf16) -> z1
  scan1<<<1024, 256, 0, stream>>>(wraw, ubuf, Ac, Sc);
  scan2<<<16, 256, 0, stream>>>(Ac, Sc, Inb);
  scan3<<<1024, 256, 0, stream>>>(wraw, ubuf, kbuf, Inb, z1);

  // groupnorm(mixed) * g -> h (bf16, into z2)
  gnorm<<<8192, 256, 0, stream>>>(z1, vbuf, gn_w, gn_b, z2);

  // out = h @ W_out^T + b_out, f32
  gemm_bt<ACT_BIAS><<<512, 512, 0, stream>>>(z2, Wb + 6 * 1048576, (float*)d_out, nullptr, b_out);
}